// Round 4
// baseline (347.518 us; speedup 1.0000x reference)
//
#include <hip/hip_runtime.h>
#include <hip/hip_bf16.h>

typedef __bf16 bf16;
typedef __bf16 bf16x4 __attribute__((ext_vector_type(4)));
typedef __bf16 bf16x8 __attribute__((ext_vector_type(8)));
typedef float  f32x4  __attribute__((ext_vector_type(4)));

// ---------------------------------------------------------------------------
// prep_w: fold Haar linearity + W into bf16 weights.
// Wbf layout: [o][1280]:
//   cols 0:256            = W1 (identity path, y1 GEMM K=256)
//   cols 256+tap*256+c    = 0.5*(±W2 ±W3 ±W4)   tap: 0=p,1=q,2=r,3=s
__global__ __launch_bounds__(256) void prep_w(const float* __restrict__ w,
                                              bf16* __restrict__ wb) {
    const int o = blockIdx.x, c = threadIdx.x;   // grid 256 x 256
    const float* wr = w + o * 1024;
    const float w1 = wr[c], w2 = wr[256 + c], w3 = wr[512 + c], w4 = wr[768 + c];
    bf16* wo_ = wb + o * 1280;
    wo_[c]              = (bf16)w1;
    wo_[256 + 0*256 + c] = (bf16)(0.5f * ( w2 + w3 + w4));   // p
    wo_[256 + 1*256 + c] = (bf16)(0.5f * ( w2 - w3 - w4));   // q
    wo_[256 + 2*256 + c] = (bf16)(0.5f * (-w2 + w3 - w4));   // r
    wo_[256 + 3*256 + c] = (bf16)(0.5f * (-w2 - w3 + w4));   // s
}

// ---------------------------------------------------------------------------
// LDS tile: 128 rows (fine pos = dlt*64 + w) x 256 c bf16, stride 256.
// XOR bank spread: g(row) = (row&7) ^ ((row>>2)&7).
__device__ __forceinline__ int tix(int row, int chunk, int lo) {
    int g = (row & 7) ^ ((row >> 2) & 7);
    return row * 256 + (((chunk ^ g) << 3) | lo);
}

// fused_x, 512-thread blocks. Round-3 PMC: MfmaUtil 10%, VALU 5.8%, HBM 15%
// -> per-wave dependency stalls, localized in phase3 (32 serialized K-steps,
// same-step ds_read + L2 load feeding only 4 MFMA). This round: explicit
// depth-2 pipeline on BOTH af (LDS) and wf (L2) in phase3; phase1/2 untouched.
__global__ __launch_bounds__(512, 4) void fused_x(const float* __restrict__ x,
                                                  const bf16* __restrict__ W,
                                                  bf16* __restrict__ z,
                                                  bf16* __restrict__ y1) {
    __shared__ bf16 tile[128 * 256];
    const int bid = blockIdx.x;               // grid 1024 = b*128 + j*2 + half
    const int half = bid & 1, j = (bid >> 1) & 63, b = bid >> 7;
    const int t = threadIdx.x;
    const int wave = t >> 6, lane = t & 63;
    const int quad = lane >> 4, l16 = lane & 15;
    const int wo2 = wave * 32;

    // phase1: 16 float4/thread in 2 bursts of 8 (8 channels per burst)
    #pragma unroll
    for (int it = 0; it < 2; ++it) {
        const int a   = it * 512 + t;        // 0..1023 assignments
        const int c8  = a >> 5;              // chunk of 8 consecutive channels
        const int rem = a & 31;
        const int dlt = rem >> 4, w4 = rem & 15;
        const float* xp = x + (((size_t)b * 256 + c8 * 8) * 128 + (2*j + dlt)) * 128
                            + half * 64 + w4 * 4;
        float4 v[8];
        #pragma unroll
        for (int i = 0; i < 8; ++i)
            v[i] = *(const float4*)(xp + (size_t)i * 16384);   // next channel
        #pragma unroll
        for (int e = 0; e < 4; ++e) {
            bf16x8 o8;
            #pragma unroll
            for (int i = 0; i < 8; ++i) o8[i] = (bf16)((&v[i].x)[e]);
            const int pos = dlt * 64 + w4 * 4 + e;
            *(bf16x8*)&tile[tix(pos, c8, 0)] = o8;
        }
    }

    // prefetch W1 fragments for kk=0 (L2-resident; latency hidden by barrier)
    bf16x8 wf_cur[2], wf_nxt[2];
    #pragma unroll
    for (int jj = 0; jj < 2; ++jj)
        wf_cur[jj] = *(const bf16x8*)(W +
            (size_t)(wo2 + jj * 16 + l16) * 1280 + quad * 8);

    __syncthreads();

    // phase2: y1 GEMM. wave = 128 pos x 32 o. MFMA(xf, wf): D.row=pos, D.col=o
    {
        f32x4 acc[8][2] = {};
        #pragma unroll
        for (int kk = 0; kk < 256; kk += 32) {
            if (kk < 224) {
                #pragma unroll
                for (int jj = 0; jj < 2; ++jj)
                    wf_nxt[jj] = *(const bf16x8*)(W +
                        (size_t)(wo2 + jj * 16 + l16) * 1280 + kk + 32 + quad * 8);
            } else {
                // seed the z-loop pipeline: first Wf fragments (cols 256..)
                #pragma unroll
                for (int jj = 0; jj < 2; ++jj)
                    wf_nxt[jj] = *(const bf16x8*)(W +
                        (size_t)(wo2 + jj * 16 + l16) * 1280 + 256 + quad * 8);
            }
            const int kc0 = kk >> 3;
            #pragma unroll
            for (int i2 = 0; i2 < 8; ++i2) {
                const bf16x8 xf = *(const bf16x8*)&tile[tix(i2 * 16 + l16,
                                                            kc0 + quad, 0)];
                #pragma unroll
                for (int jj = 0; jj < 2; ++jj)
                    acc[i2][jj] = __builtin_amdgcn_mfma_f32_16x16x32_bf16(
                        xf, wf_cur[jj], acc[i2][jj], 0, 0, 0);
            }
            #pragma unroll
            for (int jj = 0; jj < 2; ++jj) wf_cur[jj] = wf_nxt[jj];
        }

        // after this point wf_cur = Wf(kz=0). Seed depth-2: wf_nxt = Wf(kz=32)
        #pragma unroll
        for (int jj = 0; jj < 2; ++jj)
            wf_nxt[jj] = *(const bf16x8*)(W +
                (size_t)(wo2 + jj * 16 + l16) * 1280 + 256 + 32 + quad * 8);

        // y1 epilogue: pos = i2*16 + quad*4 + r, o = wo2 + jj*16 + l16
        // (its store latency also hides the phase3 pipeline-seed loads below)
        #pragma unroll
        for (int i2 = 0; i2 < 8; ++i2) {
            int p = i2 * 16 + quad * 4;
            int h = 2 * j + (p >> 6), wc = half * 64 + (p & 63);
            #pragma unroll
            for (int jj = 0; jj < 2; ++jj) {
                int o = wo2 + jj * 16 + l16;
                bf16x4 vv;
                #pragma unroll
                for (int r = 0; r < 4; ++r) vv[r] = (bf16)acc[i2][jj][r];
                *(bf16x4*)(y1 + ((size_t)b * 256 + o) * 16384 + h * 128 + wc) = vv;
            }
        }
    }

    // phase3: z GEMM, K=1024 over (tap, c). m = 32 coarse cols (this half).
    // tap->fine: p=(dlt0,even w) q=(dlt0,odd) r=(dlt1,even) s=(dlt1,odd)
    // Depth-2 pipeline on BOTH af (LDS) and wf (L2): step kz issues loads for
    // kz+64, consumes loads issued at kz-64 -> ~2 step-times (>200 cyc) of
    // latency cover. (Round 3: same-step af load -> ~15% wave duty cycle.)
    bf16x8 af_c[2], af_n[2];
    // seed af for kz=0 (tap p: dlt=0,par=0,kc0=0) and kz=32 (kc0=4)
    #pragma unroll
    for (int mi = 0; mi < 2; ++mi) {
        af_c[mi] = *(const bf16x8*)&tile[tix(2 * (mi * 16 + l16), quad, 0)];
        af_n[mi] = *(const bf16x8*)&tile[tix(2 * (mi * 16 + l16), 4 + quad, 0)];
    }

    f32x4 acc2[2][2] = {};
    #pragma unroll
    for (int kz = 0; kz < 1024; kz += 32) {
        bf16x8 wf_2[2], af_2[2];
        if (kz < 960) {
            const int kz2 = kz + 64;
            #pragma unroll
            for (int jj = 0; jj < 2; ++jj)
                wf_2[jj] = *(const bf16x8*)(W +
                    (size_t)(wo2 + jj * 16 + l16) * 1280 + 256 + kz2 + quad * 8);
            const int tap2 = kz2 >> 8;
            const int dlt2 = tap2 >> 1, par2 = tap2 & 1;
            const int kc2 = (kz2 & 255) >> 3;
            #pragma unroll
            for (int mi = 0; mi < 2; ++mi)
                af_2[mi] = *(const bf16x8*)&tile[tix(
                    dlt2 * 64 + 2 * (mi * 16 + l16) + par2, kc2 + quad, 0)];
        }
        #pragma unroll
        for (int mi = 0; mi < 2; ++mi)
            #pragma unroll
            for (int jj = 0; jj < 2; ++jj)
                acc2[mi][jj] = __builtin_amdgcn_mfma_f32_16x16x32_bf16(
                    af_c[mi], wf_cur[jj], acc2[mi][jj], 0, 0, 0);
        #pragma unroll
        for (int mi = 0; mi < 2; ++mi) { af_c[mi] = af_n[mi]; af_n[mi] = af_2[mi]; }
        #pragma unroll
        for (int jj = 0; jj < 2; ++jj) { wf_cur[jj] = wf_nxt[jj]; wf_nxt[jj] = wf_2[jj]; }
    }

    // epilogue z: coarse col = half*32 + mi*16 + quad*4 + r, coarse row = j
    #pragma unroll
    for (int mi = 0; mi < 2; ++mi) {
        #pragma unroll
        for (int jj = 0; jj < 2; ++jj) {
            int o = wo2 + jj * 16 + l16;
            int cw = half * 32 + mi * 16 + quad * 4;
            bf16x4 vv;
            #pragma unroll
            for (int r = 0; r < 4; ++r) vv[r] = (bf16)acc2[mi][jj][r];
            *(bf16x4*)(z + ((size_t)b * 256 + o) * 4096 + j * 64 + cw) = vv;
        }
    }
}

// ---------------------------------------------------------------------------
// Separable bilinear 2x upsample, edge-clamped (== jax half-pixel):
//   horizontal pass zs[64][64] -> hup[64][128] in LDS, then vertical pass is
//   4 aligned float4 reads per 8 px. Replaces the 96-scalar-gather up8
//   (4-8-way bank conflicted) that made stats/apply ~104 us each.
#define ZS 68     // zs row stride (floats); 68%32=4 -> bank shift per row
#define HS 132    // hup row stride (floats); 132%32=4, float4 aligned

__device__ __forceinline__ void load_zplane(const bf16* zp, float* zs, int t) {
    #pragma unroll
    for (int i = 0; i < 2; ++i) {
        int idx = (i * 256 + t) * 8;
        int j = idx >> 6, k = idx & 63;
        bf16x8 v = *(const bf16x8*)(zp + idx);
        float4 a, bq;
        a.x  = (float)v[0]; a.y  = (float)v[1]; a.z  = (float)v[2]; a.w  = (float)v[3];
        bq.x = (float)v[4]; bq.y = (float)v[5]; bq.z = (float)v[6]; bq.w = (float)v[7];
        *(float4*)&zs[j * ZS + k]     = a;
        *(float4*)&zs[j * ZS + k + 4] = bq;
    }
}

// pass A: thread t -> row r = t>>2, segment seg = t&3 (16 K-cells, 32 outputs)
__device__ __forceinline__ void hup_pass(const float* zs, float* hup, int t) {
    const int r = t >> 2, seg = t & 3, k0 = seg * 16;
    const float* zr = zs + r * ZS;
    float zz[18];
    #pragma unroll
    for (int d = 0; d < 18; ++d)
        zz[d] = zr[min(max(k0 - 1 + d, 0), 63)];
    float* hr = hup + r * HS + seg * 32;
    #pragma unroll
    for (int i = 0; i < 8; ++i) {
        // outputs w = 4i..4i+3 (local), K = k0+2i
        float e0 = zz[2 * i + 1], e1 = zz[2 * i + 2];
        float4 o;
        o.x = 0.75f * e0 + 0.25f * zz[2 * i];       // even: left neighbor
        o.y = 0.75f * e0 + 0.25f * e1;              // odd : right neighbor
        o.z = 0.75f * e1 + 0.25f * e0;              // even at K+1
        o.w = 0.75f * e1 + 0.25f * zz[2 * i + 3];   // odd  at K+1
        *(float4*)&hr[4 * i] = o;
    }
}

// pass B: vertical blend for 8 consecutive px at 'base'
__device__ __forceinline__ void up8v(const float* hup, int base, float* u) {
    const int h = base >> 7, w0 = base & 127;
    const int j0 = h >> 1;
    const int jn = (h & 1) ? min(j0 + 1, 63) : max(j0 - 1, 0);
    const float* r0 = hup + j0 * HS + w0;
    const float* r1 = hup + jn * HS + w0;
    float4 a0 = *(const float4*)r0, a1 = *(const float4*)(r0 + 4);
    float4 b0 = *(const float4*)r1, b1 = *(const float4*)(r1 + 4);
    u[0] = 0.75f * a0.x + 0.25f * b0.x;  u[1] = 0.75f * a0.y + 0.25f * b0.y;
    u[2] = 0.75f * a0.z + 0.25f * b0.z;  u[3] = 0.75f * a0.w + 0.25f * b0.w;
    u[4] = 0.75f * a1.x + 0.25f * b1.x;  u[5] = 0.75f * a1.y + 0.25f * b1.y;
    u[6] = 0.75f * a1.z + 0.25f * b1.z;  u[7] = 0.75f * a1.w + 0.25f * b1.w;
}

__global__ __launch_bounds__(256) void stats_k(const bf16* __restrict__ y1,
                                               const bf16* __restrict__ z,
                                               float* __restrict__ stats) {
    __shared__ float zs[64 * ZS];
    __shared__ float hup[64 * HS];
    __shared__ float red[8];
    const int bid = blockIdx.x;               // grid 2048 = b*256 + o
    const int o = bid & 255, b = bid >> 8;
    const int t = threadIdx.x;
    const bf16* zp = z + ((size_t)b * 256 + o) * 4096;
    const bf16* yp = y1 + ((size_t)b * 256 + o) * 16384;
    load_zplane(zp, zs, t);
    // batch-issue all y loads (8x16B in flight) before the barrier waits
    bf16x8 yv[8];
    #pragma unroll
    for (int i = 0; i < 8; ++i)
        yv[i] = *(const bf16x8*)(yp + (i * 256 + t) * 8);
    __syncthreads();
    hup_pass(zs, hup, t);
    __syncthreads();
    float s = 0.f, ss = 0.f;
    #pragma unroll
    for (int i = 0; i < 8; ++i) {
        int base = (i * 256 + t) * 8;
        float u[8];
        up8v(hup, base, u);
        #pragma unroll
        for (int e = 0; e < 8; ++e) {
            float y = (float)yv[i][e] + u[e];
            s += y; ss += y * y;
        }
    }
    #pragma unroll
    for (int off = 32; off > 0; off >>= 1) {
        s += __shfl_down(s, off);
        ss += __shfl_down(ss, off);
    }
    if ((t & 63) == 0) { red[t >> 6] = s; red[4 + (t >> 6)] = ss; }
    __syncthreads();
    if (t == 0) {
        atomicAdd(&stats[o],       red[0] + red[1] + red[2] + red[3]);
        atomicAdd(&stats[256 + o], red[4] + red[5] + red[6] + red[7]);
    }
}

// apply_k: finalize folded in (mean/var/scale/shift recomputed per block from
// the raw sums -- 2 scalar loads + ~6 ops, cheaper than a dispatch).
__global__ __launch_bounds__(256) void apply_k(const bf16* __restrict__ y1,
                                               const bf16* __restrict__ z,
                                               const float* __restrict__ stats,
                                               const float* __restrict__ gamma,
                                               const float* __restrict__ beta,
                                               float* __restrict__ out) {
    __shared__ float zs[64 * ZS];
    __shared__ float hup[64 * HS];
    const int bid = blockIdx.x;
    const int o = bid & 255, b = bid >> 8;
    const int t = threadIdx.x;
    const bf16* zp = z + ((size_t)b * 256 + o) * 4096;
    const bf16* yp = y1 + ((size_t)b * 256 + o) * 16384;
    float* op = out + ((size_t)b * 256 + o) * 16384;
    const float n = 131072.f;
    float mean = stats[o] / n;
    float var = stats[256 + o] / n - mean * mean;
    float sc = rsqrtf(var + 1e-5f) * gamma[o];
    float sh = beta[o] - mean * sc;
    load_zplane(zp, zs, t);
    bf16x8 yv[8];
    #pragma unroll
    for (int i = 0; i < 8; ++i)
        yv[i] = *(const bf16x8*)(yp + (i * 256 + t) * 8);
    __syncthreads();
    hup_pass(zs, hup, t);
    __syncthreads();
    #pragma unroll
    for (int i = 0; i < 8; ++i) {
        int base = (i * 256 + t) * 8;
        float u[8];
        up8v(hup, base, u);
        float4 o0, o1;
        o0.x = fmaxf(fmaf((float)yv[i][0] + u[0], sc, sh), 0.f);
        o0.y = fmaxf(fmaf((float)yv[i][1] + u[1], sc, sh), 0.f);
        o0.z = fmaxf(fmaf((float)yv[i][2] + u[2], sc, sh), 0.f);
        o0.w = fmaxf(fmaf((float)yv[i][3] + u[3], sc, sh), 0.f);
        o1.x = fmaxf(fmaf((float)yv[i][4] + u[4], sc, sh), 0.f);
        o1.y = fmaxf(fmaf((float)yv[i][5] + u[5], sc, sh), 0.f);
        o1.z = fmaxf(fmaf((float)yv[i][6] + u[6], sc, sh), 0.f);
        o1.w = fmaxf(fmaf((float)yv[i][7] + u[7], sc, sh), 0.f);
        *(float4*)(op + base) = o0;
        *(float4*)(op + base + 4) = o1;
    }
}

// ---------------------------------------------------------------------------
extern "C" void kernel_launch(void* const* d_in, const int* in_sizes, int n_in,
                              void* d_out, int out_size, void* d_ws, size_t ws_size,
                              hipStream_t stream) {
    const float* x      = (const float*)d_in[0];   // (8,256,128,128)
    const float* conv_w = (const float*)d_in[1];   // (256,1024)
    const float* gamma  = (const float*)d_in[2];   // (256,)
    const float* beta   = (const float*)d_in[3];   // (256,)
    float* out = (float*)d_out;

    char* ws = (char*)d_ws;
    // Wbf 640K (pad 1M) | z 16M | stats 4K (pad 64K) | y1 64M   (~81 MB)
    bf16*  Wbf   = (bf16*)ws;
    bf16*  z     = (bf16*)(ws + (1ll << 20));
    float* stats = (float*)(ws + (17ll << 20));
    bf16*  y1    = (bf16*)(ws + (17ll << 20) + (1ll << 16));

    hipMemsetAsync(stats, 0, 4096, stream);
    prep_w<<<256, 256, 0, stream>>>(conv_w, Wbf);
    fused_x<<<1024, 512, 0, stream>>>(x, Wbf, z, y1);
    stats_k<<<2048, 256, 0, stream>>>(y1, z, stats);
    apply_k<<<2048, 256, 0, stream>>>(y1, z, stats, gamma, beta, out);
}

// Round 5
// 339.871 us; speedup vs baseline: 1.0225x; 1.0225x over previous
//
#include <hip/hip_runtime.h>
#include <hip/hip_bf16.h>

typedef __bf16 bf16;
typedef __bf16 bf16x4 __attribute__((ext_vector_type(4)));
typedef __bf16 bf16x8 __attribute__((ext_vector_type(8)));
typedef float  f32x4  __attribute__((ext_vector_type(4)));

// ---------------------------------------------------------------------------
// prep_w: fold Haar linearity + W into bf16 weights.
// Wbf layout: [o][1280]:
//   cols 0:256            = W1 (identity path, y1 GEMM K=256)
//   cols 256+tap*256+c    = 0.5*(±W2 ±W3 ±W4)   tap: 0=p,1=q,2=r,3=s
__global__ __launch_bounds__(256) void prep_w(const float* __restrict__ w,
                                              bf16* __restrict__ wb) {
    const int o = blockIdx.x, c = threadIdx.x;   // grid 256 x 256
    const float* wr = w + o * 1024;
    const float w1 = wr[c], w2 = wr[256 + c], w3 = wr[512 + c], w4 = wr[768 + c];
    bf16* wo_ = wb + o * 1280;
    wo_[c]              = (bf16)w1;
    wo_[256 + 0*256 + c] = (bf16)(0.5f * ( w2 + w3 + w4));   // p
    wo_[256 + 1*256 + c] = (bf16)(0.5f * ( w2 - w3 - w4));   // q
    wo_[256 + 2*256 + c] = (bf16)(0.5f * (-w2 + w3 - w4));   // r
    wo_[256 + 3*256 + c] = (bf16)(0.5f * (-w2 - w3 + w4));   // s
}

// ---------------------------------------------------------------------------
// LDS tile: 128 rows (fine pos = dlt*64 + w) x 256 c bf16, stride 256.
// XOR bank spread: g(row) = (row&7) ^ ((row>>2)&7).
__device__ __forceinline__ int tix(int row, int chunk, int lo) {
    int g = (row & 7) ^ ((row >> 2) & 7);
    return row * 256 + (((chunk ^ g) << 3) | lo);
}

// fused_x, 512-thread blocks.
// Rounds 3-4 lesson: VGPR_Count stayed 60 -> compiler sank every source-level
// prefetch; phase3's per-step W loads serialized (MfmaUtil 10%).
// This round: phase3 W-fragments are LOOP-INVARIANT. Per tap (K=256), all 16
// fragments for this wave's 32 o-cols are loaded into registers up front
// (16 KB/wave in flight, depth-16), pinned by sched_barrier(0); the 8-step
// MFMA loop then has NO global dependency at all.
__global__ __launch_bounds__(512, 4) void fused_x(const float* __restrict__ x,
                                                  const bf16* __restrict__ W,
                                                  bf16* __restrict__ z,
                                                  bf16* __restrict__ y1) {
    __shared__ bf16 tile[128 * 256];
    const int bid = blockIdx.x;               // grid 1024 = b*128 + j*2 + half
    const int half = bid & 1, j = (bid >> 1) & 63, b = bid >> 7;
    const int t = threadIdx.x;
    const int wave = t >> 6, lane = t & 63;
    const int quad = lane >> 4, l16 = lane & 15;
    const int wo2 = wave * 32;

    // phase1: 16 float4/thread in 2 bursts of 8 (8 channels per burst)
    #pragma unroll
    for (int it = 0; it < 2; ++it) {
        const int a   = it * 512 + t;        // 0..1023 assignments
        const int c8  = a >> 5;              // chunk of 8 consecutive channels
        const int rem = a & 31;
        const int dlt = rem >> 4, w4 = rem & 15;
        const float* xp = x + (((size_t)b * 256 + c8 * 8) * 128 + (2*j + dlt)) * 128
                            + half * 64 + w4 * 4;
        float4 v[8];
        #pragma unroll
        for (int i = 0; i < 8; ++i)
            v[i] = *(const float4*)(xp + (size_t)i * 16384);   // next channel
        #pragma unroll
        for (int e = 0; e < 4; ++e) {
            bf16x8 o8;
            #pragma unroll
            for (int i = 0; i < 8; ++i) o8[i] = (bf16)((&v[i].x)[e]);
            const int pos = dlt * 64 + w4 * 4 + e;
            *(bf16x8*)&tile[tix(pos, c8, 0)] = o8;
        }
    }

    // prefetch W1 fragments for kk=0 (L2-resident; latency hidden by barrier)
    bf16x8 wf_cur[2], wf_nxt[2];
    #pragma unroll
    for (int jj = 0; jj < 2; ++jj)
        wf_cur[jj] = *(const bf16x8*)(W +
            (size_t)(wo2 + jj * 16 + l16) * 1280 + quad * 8);

    __syncthreads();

    // phase2: y1 GEMM. wave = 128 pos x 32 o. MFMA(xf, wf): D.row=pos, D.col=o
    {
        f32x4 acc[8][2] = {};
        #pragma unroll
        for (int kk = 0; kk < 256; kk += 32) {
            if (kk < 224) {
                #pragma unroll
                for (int jj = 0; jj < 2; ++jj)
                    wf_nxt[jj] = *(const bf16x8*)(W +
                        (size_t)(wo2 + jj * 16 + l16) * 1280 + kk + 32 + quad * 8);
            }
            const int kc0 = kk >> 3;
            #pragma unroll
            for (int i2 = 0; i2 < 8; ++i2) {
                const bf16x8 xf = *(const bf16x8*)&tile[tix(i2 * 16 + l16,
                                                            kc0 + quad, 0)];
                #pragma unroll
                for (int jj = 0; jj < 2; ++jj)
                    acc[i2][jj] = __builtin_amdgcn_mfma_f32_16x16x32_bf16(
                        xf, wf_cur[jj], acc[i2][jj], 0, 0, 0);
            }
            if (kk < 224) {
                #pragma unroll
                for (int jj = 0; jj < 2; ++jj) wf_cur[jj] = wf_nxt[jj];
            }
        }

        // y1 epilogue: pos = i2*16 + quad*4 + r, o = wo2 + jj*16 + l16
        #pragma unroll
        for (int i2 = 0; i2 < 8; ++i2) {
            int p = i2 * 16 + quad * 4;
            int h = 2 * j + (p >> 6), wc = half * 64 + (p & 63);
            #pragma unroll
            for (int jj = 0; jj < 2; ++jj) {
                int o = wo2 + jj * 16 + l16;
                bf16x4 vv;
                #pragma unroll
                for (int r = 0; r < 4; ++r) vv[r] = (bf16)acc[i2][jj][r];
                *(bf16x4*)(y1 + ((size_t)b * 256 + o) * 16384 + h * 128 + wc) = vv;
            }
        }
    }

    // phase3: z GEMM, K=1024 over (tap, c). m = 32 coarse cols (this half).
    // tap->fine: p=(dlt0,even w) q=(dlt0,odd) r=(dlt1,even) s=(dlt1,odd)
    // Per tap: 16 register-resident W frags (64 VGPR) loaded up front, then a
    // pure LDS+MFMA loop. sched_barrier(0) pins the load block.
    f32x4 acc2[2][2] = {};
    #pragma unroll
    for (int tap = 0; tap < 4; ++tap) {
        const int dlt = tap >> 1, par = tap & 1;
        bf16x8 wfc[16];
        #pragma unroll
        for (int s = 0; s < 16; ++s)
            wfc[s] = *(const bf16x8*)(W +
                (size_t)(wo2 + (s & 1) * 16 + l16) * 1280 +
                256 + tap * 256 + (s >> 1) * 32 + quad * 8);
        __builtin_amdgcn_sched_barrier(0);
        #pragma unroll
        for (int ks = 0; ks < 8; ++ks) {
            bf16x8 af[2];
            #pragma unroll
            for (int mi = 0; mi < 2; ++mi)
                af[mi] = *(const bf16x8*)&tile[tix(
                    dlt * 64 + 2 * (mi * 16 + l16) + par, ks * 4 + quad, 0)];
            #pragma unroll
            for (int mi = 0; mi < 2; ++mi)
                #pragma unroll
                for (int jj = 0; jj < 2; ++jj)
                    acc2[mi][jj] = __builtin_amdgcn_mfma_f32_16x16x32_bf16(
                        af[mi], wfc[ks * 2 + jj], acc2[mi][jj], 0, 0, 0);
        }
    }

    // epilogue z: coarse col = half*32 + mi*16 + quad*4 + r, coarse row = j
    #pragma unroll
    for (int mi = 0; mi < 2; ++mi) {
        #pragma unroll
        for (int jj = 0; jj < 2; ++jj) {
            int o = wo2 + jj * 16 + l16;
            int cw = half * 32 + mi * 16 + quad * 4;
            bf16x4 vv;
            #pragma unroll
            for (int r = 0; r < 4; ++r) vv[r] = (bf16)acc2[mi][jj][r];
            *(bf16x4*)(z + ((size_t)b * 256 + o) * 4096 + j * 64 + cw) = vv;
        }
    }
}

// ---------------------------------------------------------------------------
// Bilinear 2x upsample, edge-clamped (== jax). Round-4 lesson: stats/apply
// are insensitive to LDS instruction count -> latency x block-rounds bound.
// This round: 4x parallelism. Each block handles a 32-fine-row segment of one
// (b,o) plane; loads only the 18 coarse z-rows it needs (4.9 KB LDS) ->
// 8 blocks/CU (was 3), per-block critical path ~4x shorter.
#define ZS 68     // zs row stride (floats); float4-aligned, bank shift 4/row

// vertical+horizontal gather for 8 consecutive px at global index gbase
__device__ __forceinline__ void up8s(const float* zs, int gbase, int base_j,
                                     float* u) {
    const int h = gbase >> 7, w0 = gbase & 127;
    const int j0 = h >> 1;
    const int jn = (h & 1) ? min(j0 + 1, 63) : max(j0 - 1, 0);
    const float* r0 = zs + (j0 - base_j) * ZS;
    const float* r1 = zs + (jn - base_j) * ZS;
    const int K = w0 >> 1;
    float z0[6], z1[6];
    #pragma unroll
    for (int d = 0; d < 6; ++d) {
        int kc = min(max(K - 1 + d, 0), 63);
        z0[d] = r0[kc];
        z1[d] = r1[kc];
    }
    #pragma unroll
    for (int e = 0; e < 8; ++e) {
        int a = (e >> 1) + 1;
        int bb = (e & 1) ? a + 1 : a - 1;
        u[e] = 0.5625f * z0[a] + 0.1875f * (z0[bb] + z1[a]) + 0.0625f * z1[bb];
    }
}

// load the 18 coarse z-rows [base_j .. base_j+17] (row-clamped) into zs
__device__ __forceinline__ void load_zseg(const bf16* zp, float* zs,
                                          int base_j, int t) {
    if (t < 144) {
        const int r = t >> 3, k8 = t & 7;
        const int gr = min(max(base_j + r, 0), 63);
        bf16x8 v = *(const bf16x8*)(zp + gr * 64 + k8 * 8);
        float4 a, bq;
        a.x  = (float)v[0]; a.y  = (float)v[1]; a.z  = (float)v[2]; a.w  = (float)v[3];
        bq.x = (float)v[4]; bq.y = (float)v[5]; bq.z = (float)v[6]; bq.w = (float)v[7];
        *(float4*)&zs[r * ZS + k8 * 8]     = a;
        *(float4*)&zs[r * ZS + k8 * 8 + 4] = bq;
    }
}

__global__ __launch_bounds__(256) void stats_k(const bf16* __restrict__ y1,
                                               const bf16* __restrict__ z,
                                               float* __restrict__ stats) {
    __shared__ float zs[18 * ZS];
    __shared__ float red[8];
    const int bid = blockIdx.x;        // grid 8192 = (b*256 + o)*4 + seg
    const int seg = bid & 3, o = (bid >> 2) & 255, b = bid >> 10;
    const int t = threadIdx.x;
    const int base_j = seg * 16 - 1;
    const bf16* zp = z + ((size_t)b * 256 + o) * 4096;
    const bf16* yp = y1 + ((size_t)b * 256 + o) * 16384 + seg * 4096;
    load_zseg(zp, zs, base_j, t);
    bf16x8 yv[2];
    yv[0] = *(const bf16x8*)(yp + t * 8);
    yv[1] = *(const bf16x8*)(yp + 2048 + t * 8);
    __syncthreads();
    float s = 0.f, ss = 0.f;
    #pragma unroll
    for (int i = 0; i < 2; ++i) {
        const int gbase = seg * 4096 + i * 2048 + t * 8;
        float u[8];
        up8s(zs, gbase, base_j, u);
        #pragma unroll
        for (int e = 0; e < 8; ++e) {
            float y = (float)yv[i][e] + u[e];
            s += y; ss += y * y;
        }
    }
    #pragma unroll
    for (int off = 32; off > 0; off >>= 1) {
        s += __shfl_down(s, off);
        ss += __shfl_down(ss, off);
    }
    if ((t & 63) == 0) { red[t >> 6] = s; red[4 + (t >> 6)] = ss; }
    __syncthreads();
    if (t == 0) {
        atomicAdd(&stats[o],       red[0] + red[1] + red[2] + red[3]);
        atomicAdd(&stats[256 + o], red[4] + red[5] + red[6] + red[7]);
    }
}

// apply_k: finalize folded in (mean/var/scale/shift recomputed per block from
// the raw sums -- 2 scalar loads + ~6 ops, cheaper than a dispatch).
__global__ __launch_bounds__(256) void apply_k(const bf16* __restrict__ y1,
                                               const bf16* __restrict__ z,
                                               const float* __restrict__ stats,
                                               const float* __restrict__ gamma,
                                               const float* __restrict__ beta,
                                               float* __restrict__ out) {
    __shared__ float zs[18 * ZS];
    const int bid = blockIdx.x;        // grid 8192 = (b*256 + o)*4 + seg
    const int seg = bid & 3, o = (bid >> 2) & 255, b = bid >> 10;
    const int t = threadIdx.x;
    const int base_j = seg * 16 - 1;
    const bf16* zp = z + ((size_t)b * 256 + o) * 4096;
    const bf16* yp = y1 + ((size_t)b * 256 + o) * 16384 + seg * 4096;
    float* op = out + ((size_t)b * 256 + o) * 16384 + seg * 4096;
    const float n = 131072.f;
    float mean = stats[o] / n;
    float var = stats[256 + o] / n - mean * mean;
    float sc = rsqrtf(var + 1e-5f) * gamma[o];
    float sh = beta[o] - mean * sc;
    load_zseg(zp, zs, base_j, t);
    bf16x8 yv[2];
    yv[0] = *(const bf16x8*)(yp + t * 8);
    yv[1] = *(const bf16x8*)(yp + 2048 + t * 8);
    __syncthreads();
    #pragma unroll
    for (int i = 0; i < 2; ++i) {
        const int lbase = i * 2048 + t * 8;
        const int gbase = seg * 4096 + lbase;
        float u[8];
        up8s(zs, gbase, base_j, u);
        float4 o0, o1;
        o0.x = fmaxf(fmaf((float)yv[i][0] + u[0], sc, sh), 0.f);
        o0.y = fmaxf(fmaf((float)yv[i][1] + u[1], sc, sh), 0.f);
        o0.z = fmaxf(fmaf((float)yv[i][2] + u[2], sc, sh), 0.f);
        o0.w = fmaxf(fmaf((float)yv[i][3] + u[3], sc, sh), 0.f);
        o1.x = fmaxf(fmaf((float)yv[i][4] + u[4], sc, sh), 0.f);
        o1.y = fmaxf(fmaf((float)yv[i][5] + u[5], sc, sh), 0.f);
        o1.z = fmaxf(fmaf((float)yv[i][6] + u[6], sc, sh), 0.f);
        o1.w = fmaxf(fmaf((float)yv[i][7] + u[7], sc, sh), 0.f);
        *(float4*)(op + lbase) = o0;
        *(float4*)(op + lbase + 4) = o1;
    }
}

// ---------------------------------------------------------------------------
extern "C" void kernel_launch(void* const* d_in, const int* in_sizes, int n_in,
                              void* d_out, int out_size, void* d_ws, size_t ws_size,
                              hipStream_t stream) {
    const float* x      = (const float*)d_in[0];   // (8,256,128,128)
    const float* conv_w = (const float*)d_in[1];   // (256,1024)
    const float* gamma  = (const float*)d_in[2];   // (256,)
    const float* beta   = (const float*)d_in[3];   // (256,)
    float* out = (float*)d_out;

    char* ws = (char*)d_ws;
    // Wbf 640K (pad 1M) | z 16M | stats 4K (pad 64K) | y1 64M   (~81 MB)
    bf16*  Wbf   = (bf16*)ws;
    bf16*  z     = (bf16*)(ws + (1ll << 20));
    float* stats = (float*)(ws + (17ll << 20));
    bf16*  y1    = (bf16*)(ws + (17ll << 20) + (1ll << 16));

    hipMemsetAsync(stats, 0, 4096, stream);
    prep_w<<<256, 256, 0, stream>>>(conv_w, Wbf);
    fused_x<<<1024, 512, 0, stream>>>(x, Wbf, z, y1);
    stats_k<<<8192, 256, 0, stream>>>(y1, z, stats);
    apply_k<<<8192, 256, 0, stream>>>(y1, z, stats, gamma, beta, out);
}